// Round 1
// baseline (1216.839 us; speedup 1.0000x reference)
//
#include <hip/hip_runtime.h>
#include <math.h>

#define N_NODES 40000
#define D 128
#define NEDGE 640000
#define EMPTY 0xFFFFFFFFu

__device__ __forceinline__ unsigned hash_mix(unsigned k) {
    k ^= k >> 16; k *= 0x85ebca6bu; k ^= k >> 13; k *= 0xc2b2ae35u; k ^= k >> 16;
    return k;
}

// Zero the y accumulator (lives in d_out: [N,256] = y_re|y_im), deg, and hash sentinel.
__global__ void init_kernel(float* __restrict__ y, float* __restrict__ deg,
                            unsigned* __restrict__ hashtab, int hsize) {
    int i = blockIdx.x * blockDim.x + threadIdx.x;
    int stride = gridDim.x * blockDim.x;
    float4* y4 = (float4*)y;
    const int y4n = N_NODES * 2 * D / 4;
    for (int t = i; t < y4n; t += stride) y4[t] = make_float4(0.f, 0.f, 0.f, 0.f);
    for (int t = i; t < hsize; t += stride) hashtab[t] = EMPTY;
    for (int t = i; t < N_NODES; t += stride) deg[t] = 0.f;
}

// Wc = 0.5*(W1+W2), bc = 0.5*(b1+b2)   (ALPHA = 0.5 exactly)
__global__ void prep_lin_kernel(const float* __restrict__ W1, const float* __restrict__ b1,
                                const float* __restrict__ W2, const float* __restrict__ b2,
                                float* __restrict__ Wc, float* __restrict__ bc) {
    int i = blockIdx.x * blockDim.x + threadIdx.x;
    if (i < D * D) Wc[i] = 0.5f * (W1[i] + W2[i]);
    if (i < D) bc[i] = 0.5f * (b1[i] + b2[i]);
}

// Insert all directed-edge keys into the hash set; accumulate symmetrized degree.
__global__ void build_kernel(const int* __restrict__ row, const int* __restrict__ col,
                             float* __restrict__ deg, unsigned* __restrict__ hashtab,
                             unsigned hmask) {
    int e = blockIdx.x * blockDim.x + threadIdx.x;
    if (e >= NEDGE) return;
    int r = row[e], c = col[e];
    unsigned key = (unsigned)r * (unsigned)N_NODES + (unsigned)c;
    unsigned h = hash_mix(key) & hmask;
    while (true) {
        unsigned prev = atomicCAS(&hashtab[h], EMPTY, key);
        if (prev == EMPTY || prev == key) break;
        h = (h + 1) & hmask;
    }
    atomicAdd(&deg[r], 0.5f);
    atomicAdd(&deg[c], 0.5f);
}

// deg -> dinv in place
__global__ void dinv_kernel(float* __restrict__ deg) {
    int i = blockIdx.x * blockDim.x + threadIdx.x;
    if (i < N_NODES) {
        float d = deg[i];
        deg[i] = (d > 0.f) ? 1.0f / sqrtf(d) : 0.f;
    }
}

// One wave per directed edge. Each lane handles a float2 chunk of the 128-dim row.
// Bidirectional edge -> real part (+s both directions).
// Unidirectional -> imag part (+s forward copy, -s reversed copy).
__global__ __launch_bounds__(256) void scatter_kernel(
    const float* __restrict__ x, const int* __restrict__ row, const int* __restrict__ col,
    const float* __restrict__ dinv, const unsigned* __restrict__ hashtab, unsigned hmask,
    float* __restrict__ y) {
    int e = blockIdx.x * 4 + (threadIdx.x >> 6);
    if (e >= NEDGE) return;
    int lane = threadIdx.x & 63;
    int r = row[e], c = col[e];
    float s = 0.5f * dinv[r] * dinv[c];

    unsigned rkey = (unsigned)c * (unsigned)N_NODES + (unsigned)r;
    unsigned h = hash_mix(rkey) & hmask;
    bool rev = false;
    while (true) {
        unsigned v = hashtab[h];
        if (v == rkey) { rev = true; break; }
        if (v == EMPTY) break;
        h = (h + 1) & hmask;
    }

    const float2* xr = (const float2*)(x + (size_t)r * D);
    const float2* xc = (const float2*)(x + (size_t)c * D);
    float2 ac = xc[lane];   // feeds node r
    float2 ar = xr[lane];   // feeds node c

    float* yr; float* yc; float sc;
    if (rev) {
        yr = y + (size_t)r * 256 + 2 * lane;          // real part
        yc = y + (size_t)c * 256 + 2 * lane;
        sc = s;
    } else {
        yr = y + (size_t)r * 256 + 128 + 2 * lane;    // imag part
        yc = y + (size_t)c * 256 + 128 + 2 * lane;
        sc = -s;
    }
    atomicAdd(yr,     s * ac.x);
    atomicAdd(yr + 1, s * ac.y);
    atomicAdd(yc,     sc * ar.x);
    atomicAdd(yc + 1, sc * ar.y);
}

// In-place fused linear: out[u] = y[u] @ Wc + bc for both halves (re|im share Wc, bc).
// 8 nodes per block; y rows staged in LDS; each thread owns one (half, col).
#define NPB 8
__global__ __launch_bounds__(256) void linear_kernel(
    float* __restrict__ y, const float* __restrict__ Wc, const float* __restrict__ bc) {
    __shared__ float ylds[NPB * 256];
    int node0 = blockIdx.x * NPB;
    int tid = threadIdx.x;

    const float4* src = (const float4*)(y + (size_t)node0 * 256);
    float4* dst4 = (float4*)ylds;
    #pragma unroll
    for (int t = tid; t < NPB * 64; t += 256) dst4[t] = src[t];
    __syncthreads();

    int colj = tid & 127;
    int half = tid >> 7;      // 0 = real, 1 = imag
    float acc[NPB];
    #pragma unroll
    for (int q = 0; q < NPB; q++) acc[q] = 0.f;

    const float* yb = ylds + half * 128;
    #pragma unroll 4
    for (int k = 0; k < 128; k++) {
        float w = Wc[k * 128 + colj];
        #pragma unroll
        for (int q = 0; q < NPB; q++) acc[q] += yb[q * 256 + k] * w;
    }
    float bb = bc[colj];
    #pragma unroll
    for (int q = 0; q < NPB; q++)
        y[(size_t)(node0 + q) * 256 + half * 128 + colj] = acc[q] + bb;
}

extern "C" void kernel_launch(void* const* d_in, const int* in_sizes, int n_in,
                              void* d_out, int out_size, void* d_ws, size_t ws_size,
                              hipStream_t stream) {
    const float* x  = (const float*)d_in[0];
    const int*   ei = (const int*)d_in[1];
    const float* W1 = (const float*)d_in[2];
    const float* b1 = (const float*)d_in[3];
    const float* W2 = (const float*)d_in[4];
    const float* b2 = (const float*)d_in[5];
    float* out = (float*)d_out;
    const int* row = ei;
    const int* col = ei + NEDGE;

    char* ws = (char*)d_ws;
    float* Wc  = (float*)ws;              // 65536 B
    float* bc  = (float*)(ws + 65536);    // 512 B  (ends 66048)
    float* deg = (float*)(ws + 66048);    // 160000 B (ends 226048)
    unsigned hsize = 1u << 21;
    while ((size_t)226048 + (size_t)hsize * 4 > ws_size && hsize > (1u << 20)) hsize >>= 1;
    unsigned* hashtab = (unsigned*)(ws + 226048);
    unsigned hmask = hsize - 1;

    init_kernel<<<2048, 256, 0, stream>>>(out, deg, hashtab, (int)hsize);
    prep_lin_kernel<<<64, 256, 0, stream>>>(W1, b1, W2, b2, Wc, bc);
    build_kernel<<<(NEDGE + 255) / 256, 256, 0, stream>>>(row, col, deg, hashtab, hmask);
    dinv_kernel<<<(N_NODES + 255) / 256, 256, 0, stream>>>(deg);
    scatter_kernel<<<NEDGE / 4, 256, 0, stream>>>(x, row, col, deg, hashtab, hmask, out);
    linear_kernel<<<N_NODES / NPB, 256, 0, stream>>>(out, Wc, bc);
}

// Round 3
// 353.496 us; speedup vs baseline: 3.4423x; 3.4423x over previous
//
#include <hip/hip_runtime.h>
#include <math.h>

#define N_NODES 40000
#define D 128
#define NEDGE 640000
#define NBLK 157            // ceil(40000/256)
#define EMPTY 0xFFFFFFFFu

__device__ __forceinline__ unsigned hash_mix(unsigned k) {
    k ^= k >> 16; k *= 0x85ebca6bu; k ^= k >> 13; k *= 0xc2b2ae35u; k ^= k >> 16;
    return k;
}

// Reset hash sentinel + per-node counts.
__global__ void init_kernel(int* __restrict__ count, unsigned* __restrict__ hashtab, int hsize) {
    int i = blockIdx.x * blockDim.x + threadIdx.x;
    int stride = gridDim.x * blockDim.x;
    for (int t = i; t < hsize; t += stride) hashtab[t] = EMPTY;
    for (int t = i; t < N_NODES; t += stride) count[t] = 0;
}

// Wc = 0.5*(W1+W2), bc = 0.5*(b1+b2)  (ALPHA = 0.5 exactly)
__global__ void prep_lin_kernel(const float* __restrict__ W1, const float* __restrict__ b1,
                                const float* __restrict__ W2, const float* __restrict__ b2,
                                float* __restrict__ Wc, float* __restrict__ bc) {
    int i = blockIdx.x * blockDim.x + threadIdx.x;
    if (i < D * D) Wc[i] = 0.5f * (W1[i] + W2[i]);
    if (i < D) bc[i] = 0.5f * (b1[i] + b2[i]);
}

// Hash-insert all directed edges; count entries per destination (2 per edge).
__global__ void build_kernel(const int* __restrict__ row, const int* __restrict__ col,
                             int* __restrict__ count, unsigned* __restrict__ hashtab,
                             unsigned hmask) {
    int e = blockIdx.x * blockDim.x + threadIdx.x;
    if (e >= NEDGE) return;
    int r = row[e], c = col[e];
    unsigned key = (unsigned)r * (unsigned)N_NODES + (unsigned)c;
    unsigned h = hash_mix(key) & hmask;
    for (unsigned it = 0; it <= hmask; ++it) {
        unsigned prev = atomicCAS(&hashtab[h], EMPTY, key);
        if (prev == EMPTY || prev == key) break;
        h = (h + 1) & hmask;
    }
    atomicAdd(&count[r], 1);
    atomicAdd(&count[c], 1);
}

// Hierarchical exclusive scan, stage 1: per-block local scan + block totals + dinv.
__global__ __launch_bounds__(256) void scan1_kernel(const int* __restrict__ count,
                                                    int* __restrict__ offsets,
                                                    int* __restrict__ bsum,
                                                    float* __restrict__ dinv) {
    __shared__ int lds[256];
    int b = blockIdx.x, tid = threadIdx.x;
    int i = b * 256 + tid;
    int v = (i < N_NODES) ? count[i] : 0;
    if (i < N_NODES) dinv[i] = (v > 0) ? 1.0f / sqrtf(0.5f * (float)v) : 0.f;
    lds[tid] = v;
    __syncthreads();
    #pragma unroll
    for (int off = 1; off < 256; off <<= 1) {
        int t = (tid >= off) ? lds[tid - off] : 0;
        __syncthreads();
        lds[tid] += t;
        __syncthreads();
    }
    if (i < N_NODES) offsets[i] = lds[tid] - v;   // local exclusive
    if (tid == 255) bsum[b] = lds[255];           // block total
}

// Stage 2: exclusive scan of the 157 block totals (single 256-thread block).
__global__ __launch_bounds__(256) void scan2_kernel(int* __restrict__ bsum,
                                                    int* __restrict__ offsets) {
    __shared__ int lds[256];
    int tid = threadIdx.x;
    int v = (tid < NBLK) ? bsum[tid] : 0;
    lds[tid] = v;
    __syncthreads();
    #pragma unroll
    for (int off = 1; off < 256; off <<= 1) {
        int t = (tid >= off) ? lds[tid - off] : 0;
        __syncthreads();
        lds[tid] += t;
        __syncthreads();
    }
    if (tid < NBLK) bsum[tid] = lds[tid] - v;     // exclusive
    if (tid == 0) offsets[N_NODES] = 2 * NEDGE;
}

// Stage 3: add scanned block offsets; init cursors.
__global__ void scan3_kernel(int* __restrict__ offsets, const int* __restrict__ bsum,
                             int* __restrict__ cursor) {
    int b = blockIdx.x;
    int i = b * 256 + threadIdx.x;
    if (i < N_NODES) {
        int o = offsets[i] + bsum[b];
        offsets[i] = o;
        cursor[i] = o;
    }
}

// Each directed edge emits two packed entries: src | isReal<<16 | negate<<17.
// Bidirectional -> real (+ both dirs). Unidirectional -> imag (+ fwd, - reversed copy).
__global__ void expand_kernel(const int* __restrict__ row, const int* __restrict__ col,
                              const unsigned* __restrict__ hashtab, unsigned hmask,
                              int* __restrict__ cursor, unsigned* __restrict__ entries) {
    int e = blockIdx.x * blockDim.x + threadIdx.x;
    if (e >= NEDGE) return;
    int r = row[e], c = col[e];
    unsigned rkey = (unsigned)c * (unsigned)N_NODES + (unsigned)r;
    unsigned h = hash_mix(rkey) & hmask;
    bool rev = false;
    for (unsigned it = 0; it <= hmask; ++it) {
        unsigned v = hashtab[h];
        if (v == rkey) { rev = true; break; }
        if (v == EMPTY) break;
        h = (h + 1) & hmask;
    }
    unsigned fre = rev ? 0x10000u : 0u;
    int p1 = atomicAdd(&cursor[r], 1);
    if ((unsigned)p1 < 2u * NEDGE) entries[p1] = (unsigned)c | fre;
    int p2 = atomicAdd(&cursor[c], 1);
    if ((unsigned)p2 < 2u * NEDGE) entries[p2] = (unsigned)r | fre | (rev ? 0u : 0x20000u);
}

// Fused gather + linear. 2 nodes per 256-thread block; d_out written exactly once,
// never read (avoids cross-kernel RMW on d_out under graph replay).
__global__ __launch_bounds__(256) void fused_kernel(
    const float* __restrict__ x, const unsigned* __restrict__ entries,
    const int* __restrict__ offsets, const float* __restrict__ dinv,
    const float* __restrict__ Wc, const float* __restrict__ bc,
    float* __restrict__ out) {
    __shared__ float ylds[512];          // 2 nodes x (re[128] | im[128])
    __shared__ unsigned selds[2][128];
    __shared__ float sscale[2][128];
    __shared__ int nch_s[2];

    int tid = threadIdx.x;
    int sub = tid >> 7;                  // node within block
    int d = tid & 127;                   // feature dim
    int u = blockIdx.x * 2 + sub;

    int start = offsets[u], end = offsets[u + 1];
    float dru = dinv[u];
    int nch = (end - start + 127) >> 7;
    if (d == 0) nch_s[sub] = nch;
    __syncthreads();
    int nchmax = max(nch_s[0], nch_s[1]);

    float accre = 0.f, accim = 0.f;
    for (int ch = 0; ch < nchmax; ++ch) {
        int base = start + (ch << 7);
        int m = end - base;              // may be <=0 when this sub is done
        if (m > 128) m = 128;
        if (d < m) {
            unsigned e = entries[base + d];
            unsigned src = e & 0xFFFFu;
            float s = 0.5f * dru * dinv[src];
            if (e & 0x20000u) s = -s;
            selds[sub][d] = e;
            sscale[sub][d] = s;
        }
        __syncthreads();
        int i = 0;
        for (; i + 4 <= m; i += 4) {
            unsigned e0 = selds[sub][i],     e1 = selds[sub][i + 1];
            unsigned e2 = selds[sub][i + 2], e3 = selds[sub][i + 3];
            float v0 = x[(size_t)(e0 & 0xFFFFu) * D + d];
            float v1 = x[(size_t)(e1 & 0xFFFFu) * D + d];
            float v2 = x[(size_t)(e2 & 0xFFFFu) * D + d];
            float v3 = x[(size_t)(e3 & 0xFFFFu) * D + d];
            float s0 = sscale[sub][i],     s1 = sscale[sub][i + 1];
            float s2 = sscale[sub][i + 2], s3 = sscale[sub][i + 3];
            if (e0 & 0x10000u) accre += s0 * v0; else accim += s0 * v0;
            if (e1 & 0x10000u) accre += s1 * v1; else accim += s1 * v1;
            if (e2 & 0x10000u) accre += s2 * v2; else accim += s2 * v2;
            if (e3 & 0x10000u) accre += s3 * v3; else accim += s3 * v3;
        }
        for (; i < m; i++) {
            unsigned e0 = selds[sub][i];
            float v0 = x[(size_t)(e0 & 0xFFFFu) * D + d];
            float s0 = sscale[sub][i];
            if (e0 & 0x10000u) accre += s0 * v0; else accim += s0 * v0;
        }
        __syncthreads();
    }

    ylds[sub * 256 + d] = accre;
    ylds[sub * 256 + 128 + d] = accim;
    __syncthreads();

    // out[u] = y[u] @ Wc + bc  (re and im halves share Wc, bc)
    float ar = 0.f, ai = 0.f;
    const float* yb = ylds + sub * 256;
    #pragma unroll 4
    for (int k = 0; k < 128; k++) {
        float w = Wc[k * 128 + d];
        ar += yb[k] * w;
        ai += yb[128 + k] * w;
    }
    float bb = bc[d];
    out[(size_t)u * 256 + d] = ar + bb;
    out[(size_t)u * 256 + 128 + d] = ai + bb;
}

extern "C" void kernel_launch(void* const* d_in, const int* in_sizes, int n_in,
                              void* d_out, int out_size, void* d_ws, size_t ws_size,
                              hipStream_t stream) {
    const float* x  = (const float*)d_in[0];
    const int*   ei = (const int*)d_in[1];
    const float* W1 = (const float*)d_in[2];
    const float* b1 = (const float*)d_in[3];
    const float* W2 = (const float*)d_in[4];
    const float* b2 = (const float*)d_in[5];
    float* out = (float*)d_out;
    const int* row = ei;
    const int* col = ei + NEDGE;

    char* ws = (char*)d_ws;
    float*    Wc      = (float*)ws;                    // 0        .. 65536
    float*    bc      = (float*)(ws + 65536);          // 65536    .. 66048
    int*      count   = (int*)(ws + 66048);            // 66048    .. 226048
    float*    dinv    = (float*)(ws + 226048);         // 226048   .. 386048
    int*      offsets = (int*)(ws + 386048);           // 386048   .. 546052 (pad)
    int*      cursor  = (int*)(ws + 546056);           // 546056   .. 706056
    int*      bsum    = (int*)(ws + 706056);           // 706056   .. 706684 (pad)
    unsigned* entries = (unsigned*)(ws + 706688);      // 706688   .. 5826688  (2E*4)
    size_t hoff = 5826688;
    unsigned hsize = (hoff + (size_t)(1u << 21) * 4 <= ws_size) ? (1u << 21) : (1u << 20);
    unsigned* hashtab = (unsigned*)(ws + hoff);
    unsigned hmask = hsize - 1;

    init_kernel<<<1024, 256, 0, stream>>>(count, hashtab, (int)hsize);
    prep_lin_kernel<<<64, 256, 0, stream>>>(W1, b1, W2, b2, Wc, bc);
    build_kernel<<<(NEDGE + 255) / 256, 256, 0, stream>>>(row, col, count, hashtab, hmask);
    scan1_kernel<<<NBLK, 256, 0, stream>>>(count, offsets, bsum, dinv);
    scan2_kernel<<<1, 256, 0, stream>>>(bsum, offsets);
    scan3_kernel<<<NBLK, 256, 0, stream>>>(offsets, bsum, cursor);
    expand_kernel<<<(NEDGE + 255) / 256, 256, 0, stream>>>(row, col, hashtab, hmask,
                                                           cursor, entries);
    fused_kernel<<<N_NODES / 2, 256, 0, stream>>>(x, entries, offsets, dinv, Wc, bc, out);
}

// Round 4
// 312.586 us; speedup vs baseline: 3.8928x; 1.1309x over previous
//
#include <hip/hip_runtime.h>
#include <math.h>

#define N_NODES 40000
#define D 128
#define NEDGE 640000
#define NBLK 157            // ceil(40000/256)
#define EMPTY 0xFFFFFFFFu

__device__ __forceinline__ unsigned hash_mix(unsigned k) {
    k ^= k >> 16; k *= 0x85ebca6bu; k ^= k >> 13; k *= 0xc2b2ae35u; k ^= k >> 16;
    return k;
}

// Reset hash sentinel + counts; fold in Wc = 0.5*(W1+W2), bc = 0.5*(b1+b2).
__global__ void init_kernel(int* __restrict__ count, unsigned* __restrict__ hashtab, int hsize,
                            const float* __restrict__ W1, const float* __restrict__ b1,
                            const float* __restrict__ W2, const float* __restrict__ b2,
                            float* __restrict__ Wc, float* __restrict__ bc) {
    int i = blockIdx.x * blockDim.x + threadIdx.x;
    int stride = gridDim.x * blockDim.x;
    for (int t = i; t < hsize; t += stride) hashtab[t] = EMPTY;
    for (int t = i; t < N_NODES; t += stride) count[t] = 0;
    for (int t = i; t < D * D; t += stride) Wc[t] = 0.5f * (W1[t] + W2[t]);
    if (i < D) bc[i] = 0.5f * (b1[i] + b2[i]);
}

// Hash-insert all directed edges; count entries per destination (2 per edge).
__global__ void build_kernel(const int* __restrict__ row, const int* __restrict__ col,
                             int* __restrict__ count, unsigned* __restrict__ hashtab,
                             unsigned hmask) {
    int e = blockIdx.x * blockDim.x + threadIdx.x;
    if (e >= NEDGE) return;
    int r = row[e], c = col[e];
    unsigned key = (unsigned)r * (unsigned)N_NODES + (unsigned)c;
    unsigned h = hash_mix(key) & hmask;
    for (unsigned it = 0; it <= hmask; ++it) {
        unsigned prev = atomicCAS(&hashtab[h], EMPTY, key);
        if (prev == EMPTY || prev == key) break;
        h = (h + 1) & hmask;
    }
    atomicAdd(&count[r], 1);
    atomicAdd(&count[c], 1);
}

// Hierarchical exclusive scan, stage 1: per-block local scan + block totals + dinv.
__global__ __launch_bounds__(256) void scan1_kernel(const int* __restrict__ count,
                                                    int* __restrict__ offsets,
                                                    int* __restrict__ bsum,
                                                    float* __restrict__ dinv) {
    __shared__ int lds[256];
    int b = blockIdx.x, tid = threadIdx.x;
    int i = b * 256 + tid;
    int v = (i < N_NODES) ? count[i] : 0;
    if (i < N_NODES) dinv[i] = (v > 0) ? 1.0f / sqrtf(0.5f * (float)v) : 0.f;
    lds[tid] = v;
    __syncthreads();
    #pragma unroll
    for (int off = 1; off < 256; off <<= 1) {
        int t = (tid >= off) ? lds[tid - off] : 0;
        __syncthreads();
        lds[tid] += t;
        __syncthreads();
    }
    if (i < N_NODES) offsets[i] = lds[tid] - v;   // local exclusive
    if (tid == 255) bsum[b] = lds[255];           // block total
}

// Stage 2: exclusive scan of the 157 block totals.
__global__ __launch_bounds__(256) void scan2_kernel(int* __restrict__ bsum,
                                                    int* __restrict__ offsets) {
    __shared__ int lds[256];
    int tid = threadIdx.x;
    int v = (tid < NBLK) ? bsum[tid] : 0;
    lds[tid] = v;
    __syncthreads();
    #pragma unroll
    for (int off = 1; off < 256; off <<= 1) {
        int t = (tid >= off) ? lds[tid - off] : 0;
        __syncthreads();
        lds[tid] += t;
        __syncthreads();
    }
    if (tid < NBLK) bsum[tid] = lds[tid] - v;     // exclusive
    if (tid == 0) offsets[N_NODES] = 2 * NEDGE;
}

// Stage 3: add scanned block offsets; init cursors.
__global__ void scan3_kernel(int* __restrict__ offsets, const int* __restrict__ bsum,
                             int* __restrict__ cursor) {
    int b = blockIdx.x;
    int i = b * 256 + threadIdx.x;
    if (i < N_NODES) {
        int o = offsets[i] + bsum[b];
        offsets[i] = o;
        cursor[i] = o;
    }
}

// Each directed edge emits two entries {src | isReal<<16, signed scale}.
// Bidirectional -> real (+s both dirs). Unidirectional -> imag (+s fwd, -s reversed).
__global__ void expand_kernel(const int* __restrict__ row, const int* __restrict__ col,
                              const float* __restrict__ dinv,
                              const unsigned* __restrict__ hashtab, unsigned hmask,
                              int* __restrict__ cursor, uint2* __restrict__ entries) {
    int e = blockIdx.x * blockDim.x + threadIdx.x;
    if (e >= NEDGE) return;
    int r = row[e], c = col[e];
    unsigned rkey = (unsigned)c * (unsigned)N_NODES + (unsigned)r;
    unsigned h = hash_mix(rkey) & hmask;
    bool rev = false;
    for (unsigned it = 0; it <= hmask; ++it) {
        unsigned v = hashtab[h];
        if (v == rkey) { rev = true; break; }
        if (v == EMPTY) break;
        h = (h + 1) & hmask;
    }
    float s = 0.5f * dinv[r] * dinv[c];
    unsigned fre = rev ? 0x10000u : 0u;
    int p1 = atomicAdd(&cursor[r], 1);
    if ((unsigned)p1 < 2u * NEDGE) entries[p1] = make_uint2((unsigned)c | fre, __float_as_uint(s));
    int p2 = atomicAdd(&cursor[c], 1);
    if ((unsigned)p2 < 2u * NEDGE)
        entries[p2] = make_uint2((unsigned)r | fre, __float_as_uint(rev ? s : -s));
}

// Fused gather + linear. 256 threads = 4 waves; each wave owns 2 nodes (32 lanes each,
// float4 per lane). Gather loop has NO __syncthreads (per-wave LDS, same-wave ordering).
// d_out written exactly once, never read.
__global__ __launch_bounds__(256) void fused_kernel(
    const float* __restrict__ x, const uint2* __restrict__ entries,
    const int* __restrict__ offsets,
    const float* __restrict__ Wc, const float* __restrict__ bc,
    float* __restrict__ out) {
    __shared__ uint4 slds[4][2][32];     // [wave][half][entry] : src, sre, sim, pad
    __shared__ float ylds[8][260];       // padded stride: banks differ across nodes

    int tid = threadIdx.x;
    int wave = tid >> 6, half = (tid >> 5) & 1, l = tid & 31;
    int n = wave * 2 + half;
    int u = blockIdx.x * 8 + n;

    int start = offsets[u], end = offsets[u + 1];
    int m = end - start;
    int nch = (m + 31) >> 5;

    float4 accre = make_float4(0.f, 0.f, 0.f, 0.f);
    float4 accim = make_float4(0.f, 0.f, 0.f, 0.f);

    for (int ch = 0; ch < nch; ++ch) {
        int idx = (ch << 5) + l;
        uint2 e = (idx < m) ? entries[start + idx] : make_uint2(0u, 0u);
        float sval = __uint_as_float(e.y);
        bool isre = (e.x & 0x10000u) != 0u;
        float sre = isre ? sval : 0.f;
        float sim = isre ? 0.f : sval;
        slds[wave][half][l] = make_uint4(e.x & 0xFFFFu, __float_as_uint(sre),
                                         __float_as_uint(sim), 0u);
        __builtin_amdgcn_wave_barrier();
        int mm = m - (ch << 5);
        if (mm > 32) mm = 32;
        #pragma unroll 2
        for (int i = 0; i < mm; ++i) {
            uint4 t = slds[wave][half][i];
            const float4* xr = (const float4*)(x + (size_t)t.x * D);
            float4 v = xr[l];
            float fre = __uint_as_float(t.y), fim = __uint_as_float(t.z);
            accre.x += fre * v.x; accre.y += fre * v.y;
            accre.z += fre * v.z; accre.w += fre * v.w;
            accim.x += fim * v.x; accim.y += fim * v.y;
            accim.z += fim * v.z; accim.w += fim * v.w;
        }
        __builtin_amdgcn_wave_barrier();
    }

    *(float4*)&ylds[n][l * 4] = accre;          // rows are 1040B: 16B-aligned
    *(float4*)&ylds[n][128 + l * 4] = accim;
    __syncthreads();

    // Linear: thread = (node n2, col-quad c). out[u2] = y[u2] @ Wc + bc, both halves.
    int n2 = tid >> 5, c = tid & 31;
    int u2 = blockIdx.x * 8 + n2;
    const float* yb = &ylds[n2][0];
    const float4* Wc4 = (const float4*)Wc;
    float4 ar = make_float4(0.f, 0.f, 0.f, 0.f);
    float4 ai = make_float4(0.f, 0.f, 0.f, 0.f);
    #pragma unroll 4
    for (int k = 0; k < 128; k += 4) {
        float4 yr4 = *(const float4*)&yb[k];
        float4 yi4 = *(const float4*)&yb[128 + k];
        #pragma unroll
        for (int j = 0; j < 4; ++j) {
            float4 w = Wc4[(k + j) * 32 + c];
            float yr = (j == 0) ? yr4.x : (j == 1) ? yr4.y : (j == 2) ? yr4.z : yr4.w;
            float yi = (j == 0) ? yi4.x : (j == 1) ? yi4.y : (j == 2) ? yi4.z : yi4.w;
            ar.x += yr * w.x; ar.y += yr * w.y; ar.z += yr * w.z; ar.w += yr * w.w;
            ai.x += yi * w.x; ai.y += yi * w.y; ai.z += yi * w.z; ai.w += yi * w.w;
        }
    }
    float4 bv = ((const float4*)bc)[c];
    ar.x += bv.x; ar.y += bv.y; ar.z += bv.z; ar.w += bv.w;
    ai.x += bv.x; ai.y += bv.y; ai.z += bv.z; ai.w += bv.w;
    *(float4*)&out[(size_t)u2 * 256 + c * 4] = ar;
    *(float4*)&out[(size_t)u2 * 256 + 128 + c * 4] = ai;
}

extern "C" void kernel_launch(void* const* d_in, const int* in_sizes, int n_in,
                              void* d_out, int out_size, void* d_ws, size_t ws_size,
                              hipStream_t stream) {
    const float* x  = (const float*)d_in[0];
    const int*   ei = (const int*)d_in[1];
    const float* W1 = (const float*)d_in[2];
    const float* b1 = (const float*)d_in[3];
    const float* W2 = (const float*)d_in[4];
    const float* b2 = (const float*)d_in[5];
    float* out = (float*)d_out;
    const int* row = ei;
    const int* col = ei + NEDGE;

    char* ws = (char*)d_ws;
    float*    Wc      = (float*)ws;                    // 0        .. 65536
    float*    bc      = (float*)(ws + 65536);          // 65536    .. 66048
    int*      count   = (int*)(ws + 66048);            // 66048    .. 226048
    float*    dinv    = (float*)(ws + 226048);         // 226048   .. 386048
    int*      offsets = (int*)(ws + 386048);           // 386048   .. 546052 (pad)
    int*      cursor  = (int*)(ws + 546056);           // 546056   .. 706056
    int*      bsum    = (int*)(ws + 706056);           // 706056   .. 706684 (pad)
    uint2*    entries = (uint2*)(ws + 706688);         // 706688   .. 10946688 (2E*8)
    size_t hoff = 10946688;
    unsigned hsize = (hoff + (size_t)(1u << 21) * 4 <= ws_size) ? (1u << 21) : (1u << 20);
    unsigned* hashtab = (unsigned*)(ws + hoff);
    unsigned hmask = hsize - 1;

    init_kernel<<<2048, 256, 0, stream>>>(count, hashtab, (int)hsize, W1, b1, W2, b2, Wc, bc);
    build_kernel<<<(NEDGE + 255) / 256, 256, 0, stream>>>(row, col, count, hashtab, hmask);
    scan1_kernel<<<NBLK, 256, 0, stream>>>(count, offsets, bsum, dinv);
    scan2_kernel<<<1, 256, 0, stream>>>(bsum, offsets);
    scan3_kernel<<<NBLK, 256, 0, stream>>>(offsets, bsum, cursor);
    expand_kernel<<<(NEDGE + 255) / 256, 256, 0, stream>>>(row, col, dinv, hashtab, hmask,
                                                           cursor, entries);
    fused_kernel<<<N_NODES / 8, 256, 0, stream>>>(x, entries, offsets, Wc, bc, out);
}